// Round 1
// baseline (1068.529 us; speedup 1.0000x reference)
//
#include <hip/hip_runtime.h>

#define HH 512
#define WW 512
#define NT 198   // timesteps in the residual (t uses t and t+1; t in [0,198))

// One block = one timestep t, one 4-row strip (128 strips of 4 rows).
// 256 threads: thread handles cols {tid, tid+256} in each of the 4 rows.
// Periodic wrap via &511. Row/col 0 double-counted (513-grid aliasing) -> weights.
__global__ __launch_bounds__(256)
void pde_residual_kernel(const float* __restrict__ in, double* __restrict__ acc) {
    const int t = blockIdx.y;
    const int strip = blockIdx.x;   // 0..127
    const int tid = threadIdx.x;

    const size_t plane = (size_t)HH * WW;
    const float* __restrict__ u  = in + (size_t)(2 * t)     * plane;
    const float* __restrict__ v  = in + (size_t)(2 * t + 1) * plane;
    const float* __restrict__ un = in + (size_t)(2 * t + 2) * plane;
    const float* __restrict__ vn = in + (size_t)(2 * t + 3) * plane;

    float su = 0.0f, sv = 0.0f;

    #pragma unroll
    for (int r = 0; r < 4; ++r) {
        const int i   = strip * 4 + r;
        const int ic  = i * WW;
        const int im1 = ((i + HH - 1) & (HH - 1)) * WW;
        const int im2 = ((i + HH - 2) & (HH - 1)) * WW;
        const int ip1 = ((i + 1) & (HH - 1)) * WW;
        const int ip2 = ((i + 2) & (HH - 1)) * WW;
        const float wi = (i == 0) ? 2.0f : 1.0f;

        #pragma unroll
        for (int half = 0; half < 2; ++half) {
            const int j   = tid + half * 256;
            const int jm1 = (j + WW - 1) & (WW - 1);
            const int jm2 = (j + WW - 2) & (WW - 1);
            const int jp1 = (j + 1) & (WW - 1);
            const int jp2 = (j + 2) & (WW - 1);

            const float uc = u[ic + j];
            const float vc = v[ic + j];
            const float nearu = u[im1 + j] + u[ip1 + j] + u[ic + jm1] + u[ic + jp1];
            const float faru  = u[im2 + j] + u[ip2 + j] + u[ic + jm2] + u[ic + jp2];
            const float nearv = v[im1 + j] + v[ip1 + j] + v[ic + jm1] + v[ic + jp1];
            const float farv  = v[im2 + j] + v[ip2 + j] + v[ic + jm2] + v[ic + jp2];

            // lap = (-5*c + 4/3*near - 1/12*far) / DX^2 ; 1/0.04 = 25
            const float lapu = (-5.0f * uc + (4.0f / 3.0f) * nearu - (1.0f / 12.0f) * faru) * 25.0f;
            const float lapv = (-5.0f * vc + (4.0f / 3.0f) * nearv - (1.0f / 12.0f) * farv) * 25.0f;

            const float ut = (un[ic + j] - uc) * 80.0f;  // 1/DT = 80
            const float vt = (vn[ic + j] - vc) * 80.0f;

            const float s  = uc * uc + vc * vc;
            const float fu = ut - (0.1f * lapu + (1.0f - s) * uc + s * vc);
            const float fv = vt - (0.1f * lapv + (1.0f - s) * vc - s * uc);

            const float w = wi * ((j == 0) ? 2.0f : 1.0f);
            su += w * fu * fu;
            sv += w * fv * fv;
        }
    }

    // wave (64-lane) shuffle reduction
    #pragma unroll
    for (int off = 32; off > 0; off >>= 1) {
        su += __shfl_down(su, off);
        sv += __shfl_down(sv, off);
    }

    __shared__ float s_u[4], s_v[4];
    const int wave = tid >> 6;
    const int lane = tid & 63;
    if (lane == 0) { s_u[wave] = su; s_v[wave] = sv; }
    __syncthreads();
    if (tid == 0) {
        const float bu = s_u[0] + s_u[1] + s_u[2] + s_u[3];
        const float bv = s_v[0] + s_v[1] + s_v[2] + s_v[3];
        atomicAdd(&acc[0], (double)bu);
        atomicAdd(&acc[1], (double)bv);
    }
}

__global__ void finalize_kernel(const double* __restrict__ acc, float* __restrict__ out) {
    if (threadIdx.x == 0) {
        const double denom = (double)NT * 513.0 * 513.0;
        out[0] = (float)(acc[0] / denom);
        out[1] = (float)(acc[1] / denom);
    }
}

extern "C" void kernel_launch(void* const* d_in, const int* in_sizes, int n_in,
                              void* d_out, int out_size, void* d_ws, size_t ws_size,
                              hipStream_t stream) {
    const float* in = (const float*)d_in[0];
    float* out = (float*)d_out;
    double* acc = (double*)d_ws;

    hipMemsetAsync(d_ws, 0, 2 * sizeof(double), stream);

    dim3 grid(HH / 4, NT);  // 128 strips x 198 timesteps
    pde_residual_kernel<<<grid, 256, 0, stream>>>(in, acc);
    finalize_kernel<<<1, 64, 0, stream>>>(acc, out);
}